// Round 6
// baseline (191.432 us; speedup 1.0000x reference)
//
#include <hip/hip_runtime.h>

// yoloLoss on MI355X — memory-bound streaming reduction.
// pred/target: (4096,14,14,30) fp32. Output: scalar fp32.
//
// R6: nt loads (R4) killed the writeback storm; main ~56us = 3.4 TB/s vs
// fills' 6.7 TB/s on the same memory. R5 (issue-early) was neutral: the
// block memory profile is still BURSTY (one 900cy load burst, then
// ~1700cy LDS+compute with nothing in flight -> ~35-50% duty cycle).
// Fix: persistent pipelined blocks, nt reg-staging, double-buffered LDS:
//   per tile: regs->LDS (compiler emits COUNTED vmcnt for reg deps),
//   lgkmcnt(0) + RAW s_barrier (vmcnt untouched), issue tile k+1's nt
//   loads, then ds_read+compute+reduce while they fly. Loads in flight
//   ~continuously; one exposed latency per block (prologue, /6 tiles).
// R2's pipelining null was storm-regime; nt+pipeline never tested (regime
// gate). Numerics: per-tile partials, same lane<->cell map, same reduce
// tree -> bitwise-identical output.

#define FEAT 30               // B*5 + C
#define CELLS 802816          // 4096*14*14
#define TPB 256
#define CPB 256               // cells per tile
#define NTILES (CELLS / CPB)  // 3136
#define NBLK 512              // persistent: 2 blocks/CU (LDS-limited)
#define F4T (CPB * FEAT / 4)  // 1920 float4 per array per tile

typedef float f32x4 __attribute__((ext_vector_type(4)));

__device__ __forceinline__ float iou_f(float x1, float y1, float w1, float h1,
                                       float x2, float y2, float w2, float h2) {
    float b1x1 = x1 - 0.5f * w1, b1x2 = x1 + 0.5f * w1;
    float b1y1 = y1 - 0.5f * h1, b1y2 = y1 + 0.5f * h1;
    float b2x1 = x2 - 0.5f * w2, b2x2 = x2 + 0.5f * w2;
    float b2y1 = y2 - 0.5f * h2, b2y2 = y2 + 0.5f * h2;
    float iw = fmaxf(fminf(b1x2, b2x2) - fmaxf(b1x1, b2x1), 0.0f);
    float ih = fmaxf(fminf(b1y2, b2y2) - fmaxf(b1y1, b2y1), 0.0f);
    float inter = iw * ih;
    float a1 = (b1x2 - b1x1) * (b1y2 - b1y1);
    float a2 = (b2x2 - b2x1) * (b2y2 - b2y1);
    return inter / (a1 + a2 - inter + 1e-6f);
}

__global__ __launch_bounds__(TPB, 2) void yolo_main_kernel(
        const float* __restrict__ pred, const float* __restrict__ tgt,
        float* __restrict__ partials) {
    // Double-buffered (pred,tgt) tile: 2*30720 B = 61440 B -> 2 blocks/CU.
    __shared__ float sbP[2][CPB * FEAT];
    __shared__ float sbT[2][CPB * FEAT];
    __shared__ float wave_sum[TPB / 64];

    const int tid  = threadIdx.x;
    const int b    = blockIdx.x;
    const bool tail = tid < (F4T - 7 * TPB); // 128 float4 tail
    // blocks 0..63 own 7 tiles, 64..511 own 6 (64*7 + 448*6 = 3136)
    const int t0  = (b < 64) ? b * 7 : 448 + (b - 64) * 6;
    const int ntl = (b < 64) ? 7 : 6;

    f32x4 pr[8], tr[8];

    // Issue one tile's nt loads into pr/tr (16B/lane, fully coalesced).
    auto issue = [&](int k) {
        const f32x4* gp = (const f32x4*)pred + (long long)(t0 + k) * F4T;
        const f32x4* gt = (const f32x4*)tgt  + (long long)(t0 + k) * F4T;
#pragma unroll
        for (int i = 0; i < 7; ++i)
            pr[i] = __builtin_nontemporal_load(&gp[tid + i * TPB]);
        if (tail) pr[7] = __builtin_nontemporal_load(&gp[tid + 7 * TPB]);
#pragma unroll
        for (int i = 0; i < 7; ++i)
            tr[i] = __builtin_nontemporal_load(&gt[tid + i * TPB]);
        if (tail) tr[7] = __builtin_nontemporal_load(&gt[tid + 7 * TPB]);
    };

    issue(0); // prologue: only exposed load latency of the whole block

    for (int k = 0; k < ntl; ++k) {
        const int pp = k & 1;

        // regs -> LDS. Compiler inserts counted vmcnt waits for pr/tr here;
        // no full drain, nothing else is outstanding at this point anyway.
        {
            f32x4* lp = (f32x4*)sbP[pp];
            f32x4* lt = (f32x4*)sbT[pp];
#pragma unroll
            for (int i = 0; i < 7; ++i) lp[tid + i * TPB] = pr[i];
            if (tail) lp[tid + 7 * TPB] = pr[7];
#pragma unroll
            for (int i = 0; i < 7; ++i) lt[tid + i * TPB] = tr[i];
            if (tail) lt[tid + 7 * TPB] = tr[7];
        }
        // Raw barrier: ds_writes visible (lgkmcnt), vmcnt NOT drained.
        asm volatile("s_waitcnt lgkmcnt(0)" ::: "memory");
        __builtin_amdgcn_sched_barrier(0);
        __builtin_amdgcn_s_barrier();
        __builtin_amdgcn_sched_barrier(0);

        // Issue next tile's loads NOW: they fly under ds_read+compute+reduce
        // (~1700cy >> 900cy HBM latency). pr/tr are free (just written).
        if (k + 1 < ntl) issue(k + 1);

        // LDS -> regs: this thread's cell (30 pred floats, 10 tgt box floats)
        const float2* pc = (const float2*)(sbP[pp] + tid * FEAT);
        const float2* tc = (const float2*)(sbT[pp] + tid * FEAT);
        float p[FEAT], t[10];
#pragma unroll
        for (int i = 0; i < FEAT / 2; ++i) {
            float2 v = pc[i]; p[2 * i] = v.x; p[2 * i + 1] = v.y;
        }
#pragma unroll
        for (int i = 0; i < 5; ++i) {
            float2 v = tc[i]; t[2 * i] = v.x; t[2 * i + 1] = v.y;
        }

        // --- per-cell YOLO loss (identical math to verified R0..R5) ---
        const bool obj0 = t[4] > 0.0f;
        const bool obj1 = t[9] > 0.0f;
        const float mf = obj0 ? 1.0f : 0.0f;

        float d0 = p[4] - t[4];
        float d1 = p[9] - t[9];
        float noobj = (obj0 ? 0.0f : d0 * d0) + (obj1 ? 0.0f : d1 * d1);

        float iou0 = iou_f(p[0], p[1], p[2], p[3], t[0], t[1], t[2], t[3]);
        float iou1 = iou_f(p[5], p[6], p[7], p[8], t[5], t[6], t[7], t[8]);
        const bool sel1 = iou1 > iou0;

        float pbx = sel1 ? p[5] : p[0];
        float pby = sel1 ? p[6] : p[1];
        float pbw = sel1 ? p[7] : p[2];
        float pbh = sel1 ? p[8] : p[3];
        float pbc = sel1 ? p[9] : p[4];
        float tbx = sel1 ? t[5] : t[0];
        float tby = sel1 ? t[6] : t[1];
        float tbw = sel1 ? t[7] : t[2];
        float tbh = sel1 ? t[8] : t[3];
        float tbc = sel1 ? t[9] : t[4];

        float dx = pbx - tbx, dy = pby - tby;
        float xy = dx * dx + dy * dy;

        float pw = sqrtf(fabsf(pbw) + 1e-6f);
        float ph = sqrtf(fabsf(pbh) + 1e-6f);
        float tw = sqrtf(obj0 ? tbw : 1.0f); // t_wh_safe
        float th = sqrtf(obj0 ? tbh : 1.0f);
        float dw = pw - tw, dh = ph - th;
        float wh = dw * dw + dh * dh;

        float dc = pbc - tbc;
        float obj_l = dc * dc;

        float nonbest = (p[4] + p[9]) - pbc;
        noobj += 0.5f * mf * nonbest * nonbest;

        // class loss: stream t[10..29] straight from LDS
        float cls = 0.0f;
#pragma unroll
        for (int i = 5; i < FEAT / 2; ++i) {
            float2 v = tc[i];
            float da = p[2 * i] - v.x;
            float db = p[2 * i + 1] - v.y;
            cls += da * da + db * db;
        }

        float cell = 5.0f * mf * (xy + wh) + mf * obj_l + 0.5f * noobj + mf * cls;

        // --- reduction: same tree (bitwise-identical partials) ---
        float v = cell;
#pragma unroll
        for (int off = 32; off > 0; off >>= 1) v += __shfl_down(v, off, 64);
        if ((tid & 63) == 0) wave_sum[tid >> 6] = v;
        asm volatile("s_waitcnt lgkmcnt(0)" ::: "memory");
        __builtin_amdgcn_sched_barrier(0);
        __builtin_amdgcn_s_barrier(); // raw: prefetch stays in flight
        __builtin_amdgcn_sched_barrier(0);
        if (tid == 0)
            partials[t0 + k] =
                wave_sum[0] + wave_sum[1] + wave_sum[2] + wave_sum[3];
        // wave_sum reuse safe: next write is after next iter's first barrier,
        // which tid0 reaches only after these reads retire.
    }
}

__global__ __launch_bounds__(TPB) void yolo_reduce_kernel(
        const float* __restrict__ partials, float* __restrict__ out) {
    __shared__ float wave_sum[TPB / 64];
    const int tid = threadIdx.x;
    float v = 0.0f;
    for (int i = tid; i < NTILES; i += TPB) v += partials[i];
#pragma unroll
    for (int off = 32; off > 0; off >>= 1) v += __shfl_down(v, off, 64);
    if ((tid & 63) == 0) wave_sum[tid >> 6] = v;
    __syncthreads();
    if (tid == 0)
        out[0] = (wave_sum[0] + wave_sum[1] + wave_sum[2] + wave_sum[3]) *
                 (1.0f / 4096.0f);
}

extern "C" void kernel_launch(void* const* d_in, const int* in_sizes, int n_in,
                              void* d_out, int out_size, void* d_ws, size_t ws_size,
                              hipStream_t stream) {
    const float* pred = (const float*)d_in[0];
    const float* tgt  = (const float*)d_in[1];
    float* out = (float*)d_out;
    float* partials = (float*)d_ws; // 3136 floats = 12.5 KB, << ws_size

    yolo_main_kernel<<<NBLK, TPB, 0, stream>>>(pred, tgt, partials);
    yolo_reduce_kernel<<<1, TPB, 0, stream>>>(partials, out);
}